// Round 1
// baseline (188.669 us; speedup 1.0000x reference)
//
#include <hip/hip_runtime.h>

// PointPillarsScatter: out[b][c][y][x] = sum_{p: coords[p]=(b,_,y,x)} vf[p][c]
// B=4, C=64, NY=496, NX=432, P=48000.
// Output: (B, C, NY, NX) float32 = 54,853,632 elems (~219 MB).
// Strategy: kernel 1 zero-fills output (float4 stores, grid-stride);
//           kernel 2 does one (pillar,channel) per thread with atomicAdd.

#define CC 64
#define GNY 496
#define GNX 432

__global__ void pp_zero_kernel(float4* __restrict__ out, int n4) {
    int stride = gridDim.x * blockDim.x;
    for (int i = blockIdx.x * blockDim.x + threadIdx.x; i < n4; i += stride) {
        out[i] = make_float4(0.f, 0.f, 0.f, 0.f);
    }
}

__global__ void pp_scatter_kernel(const float* __restrict__ vf,
                                  const int* __restrict__ coords,
                                  float* __restrict__ out,
                                  int total /* = P*C */) {
    int tid = blockIdx.x * blockDim.x + threadIdx.x;
    if (tid >= total) return;
    int p = tid >> 6;      // pillar index
    int c = tid & 63;      // channel index
    int b = coords[p * 4 + 0];
    int y = coords[p * 4 + 2];
    int x = coords[p * 4 + 3];
    float v = vf[tid];     // coalesced: consecutive lanes read consecutive floats
    int idx = (((b * CC + c) * GNY) + y) * GNX + x;
    atomicAdd(&out[idx], v);
}

extern "C" void kernel_launch(void* const* d_in, const int* in_sizes, int n_in,
                              void* d_out, int out_size, void* d_ws, size_t ws_size,
                              hipStream_t stream) {
    const float* vf     = (const float*)d_in[0];
    const int*   coords = (const int*)d_in[1];
    float*       out    = (float*)d_out;

    int total = in_sizes[0];          // P * C
    int n4 = out_size / 4;            // out_size divisible by 4

    // Zero-fill: 2048 blocks x 256 threads, grid-stride float4 stores.
    pp_zero_kernel<<<2048, 256, 0, stream>>>((float4*)out, n4);

    // Scatter-add: one thread per (pillar, channel).
    int blocks = (total + 255) / 256;
    pp_scatter_kernel<<<blocks, 256, 0, stream>>>(vf, coords, out, total);
}

// Round 2
// 56.277 us; speedup vs baseline: 3.3525x; 3.3525x over previous
//
#include <hip/hip_runtime.h>

// PointPillarsScatter: out[b][c][y][x] = sum_{p: coords[p]=(b,_,y,x)} vf[p][c]
// B=4, C=64, NY=496, NX=432, P=48000.
// Output (B,C,NY,NX) f32 = 54,853,632 elems (~219 MB).
//
// Inverted (gather) formulation:
//   k1: head[cell] = -1 for all B*NY*NX cells           (3.4 MB fill in d_ws)
//   k2: per pillar: head/next linked list via atomicExch (48K tiny atomics)
//   k3: dense pass over all outputs: walk chain, sum, float4 coalesced store.
// Only large HBM traffic is the compulsory 219 MB output write.

#define CC 64
#define GNY 496
#define GNX 432
#define S_CELLS (GNY * GNX)        // 214272 (divisible by 256)
#define NUM_CELLS (4 * S_CELLS)    // 857088

__global__ void pp_init_head(int4* __restrict__ head4, int n4) {
    int stride = gridDim.x * blockDim.x;
    for (int i = blockIdx.x * blockDim.x + threadIdx.x; i < n4; i += stride)
        head4[i] = make_int4(-1, -1, -1, -1);
}

__global__ void pp_build(const int* __restrict__ coords,
                         int* __restrict__ head,
                         int* __restrict__ nxt,
                         int P) {
    int p = blockIdx.x * blockDim.x + threadIdx.x;
    if (p >= P) return;
    int b = coords[p * 4 + 0];
    int y = coords[p * 4 + 2];
    int x = coords[p * 4 + 3];
    int s = (b * GNY + y) * GNX + x;
    int old = atomicExch(&head[s], p);
    nxt[p] = old;
}

// Block = 256 threads = 64 lanes-of-4-cells x 4 channel-groups.
// Each block covers 256 consecutive cells x all 64 channels.
// Writes: per wave, 64 lanes x float4 = 1 KB contiguous per store.
__global__ void pp_gather(const float* __restrict__ vf,
                          const int* __restrict__ head,
                          const int* __restrict__ nxt,
                          float* __restrict__ out) {
    int t = threadIdx.x;
    int lane = t & 63;
    int cg = t >> 6;                       // 0..3 -> channels cg*16 .. cg*16+15
    int s0 = blockIdx.x * 256 + lane * 4;  // 4 consecutive cells
    int b = s0 / S_CELLS;                  // blocks never straddle batches (S_CELLS%256==0)
    int r0 = s0 - b * S_CELLS;             // linear (y*NX + x) offset

    int4 h4 = *(const int4*)&head[s0];     // one head load per thread, reused 16x

    size_t outbase = (size_t)b * (CC * S_CELLS) + r0;
    #pragma unroll 4
    for (int i = 0; i < 16; ++i) {
        int c = cg * 16 + i;
        float4 acc = make_float4(0.f, 0.f, 0.f, 0.f);
        for (int p = h4.x; p >= 0; p = nxt[p]) acc.x += vf[p * CC + c];
        for (int p = h4.y; p >= 0; p = nxt[p]) acc.y += vf[p * CC + c];
        for (int p = h4.z; p >= 0; p = nxt[p]) acc.z += vf[p * CC + c];
        for (int p = h4.w; p >= 0; p = nxt[p]) acc.w += vf[p * CC + c];
        *(float4*)&out[outbase + (size_t)c * S_CELLS] = acc;
    }
}

// ---- fallback (round-1 path) if workspace is too small ----
__global__ void pp_zero_kernel(float4* __restrict__ out, int n4) {
    int stride = gridDim.x * blockDim.x;
    for (int i = blockIdx.x * blockDim.x + threadIdx.x; i < n4; i += stride)
        out[i] = make_float4(0.f, 0.f, 0.f, 0.f);
}

__global__ void pp_scatter_kernel(const float* __restrict__ vf,
                                  const int* __restrict__ coords,
                                  float* __restrict__ out,
                                  int total) {
    int tid = blockIdx.x * blockDim.x + threadIdx.x;
    if (tid >= total) return;
    int p = tid >> 6;
    int c = tid & 63;
    int b = coords[p * 4 + 0];
    int y = coords[p * 4 + 2];
    int x = coords[p * 4 + 3];
    float v = vf[tid];
    int idx = (((b * CC + c) * GNY) + y) * GNX + x;
    atomicAdd(&out[idx], v);
}

extern "C" void kernel_launch(void* const* d_in, const int* in_sizes, int n_in,
                              void* d_out, int out_size, void* d_ws, size_t ws_size,
                              hipStream_t stream) {
    const float* vf     = (const float*)d_in[0];
    const int*   coords = (const int*)d_in[1];
    float*       out    = (float*)d_out;

    int total = in_sizes[0];           // P * C
    int P = in_sizes[1] / 4;           // 48000

    size_t need = (size_t)(NUM_CELLS + P) * sizeof(int);
    if (ws_size >= need) {
        int* head = (int*)d_ws;
        int* nxt  = head + NUM_CELLS;

        pp_init_head<<<512, 256, 0, stream>>>((int4*)head, NUM_CELLS / 4);
        pp_build<<<(P + 255) / 256, 256, 0, stream>>>(coords, head, nxt, P);
        pp_gather<<<NUM_CELLS / 256, 256, 0, stream>>>(vf, head, nxt, out);
    } else {
        // fallback: zero + atomic scatter
        pp_zero_kernel<<<2048, 256, 0, stream>>>((float4*)out, out_size / 4);
        pp_scatter_kernel<<<(total + 255) / 256, 256, 0, stream>>>(vf, coords, out, total);
    }
}

// Round 3
// 47.243 us; speedup vs baseline: 3.9936x; 1.1912x over previous
//
#include <hip/hip_runtime.h>

// PointPillarsScatter: out[b][c][y][x] = sum_{p: coords[p]=(b,_,y,x)} vf[p][c]
// B=4, C=64, NY=496, NX=432, P=48000.
// Output (B,C,NY,NX) f32 = 54,853,632 elems (~219 MB).
//
// Gather formulation:
//   k1: head[cell] = -1 for all B*NY*NX cells           (3.4 MB fill in d_ws)
//   k2: per pillar: head/next linked list via atomicExch (48K tiny atomics)
//   k3: dense pass: each thread owns 4 cells x 16 channels; walks each chain
//       ONCE, loads vf as float4, accumulates into 64 registers (static idx),
//       then 16 coalesced float4 stores. Only large HBM traffic = 219 MB write.

#define CC 64
#define GNY 496
#define GNX 432
#define S_CELLS (GNY * GNX)        // 214272 (divisible by 256)
#define NUM_CELLS (4 * S_CELLS)    // 857088

__global__ void pp_init_head(int4* __restrict__ head4, int n4) {
    int stride = gridDim.x * blockDim.x;
    for (int i = blockIdx.x * blockDim.x + threadIdx.x; i < n4; i += stride)
        head4[i] = make_int4(-1, -1, -1, -1);
}

__global__ void pp_build(const int* __restrict__ coords,
                         int* __restrict__ head,
                         int* __restrict__ nxt,
                         int P) {
    int p = blockIdx.x * blockDim.x + threadIdx.x;
    if (p >= P) return;
    int b = coords[p * 4 + 0];
    int y = coords[p * 4 + 2];
    int x = coords[p * 4 + 3];
    int s = (b * GNY + y) * GNX + x;
    int old = atomicExch(&head[s], p);
    nxt[p] = old;
}

// Block = 256 threads = 64 lanes (each owning 4 consecutive cells) x 4
// channel-groups of 16. Each thread: walk 4 chains once, accumulate 64
// floats in registers, then 16 x float4 coalesced stores (1 KB/wave/store).
__global__ __launch_bounds__(256) void pp_gather(const float4* __restrict__ vf4,
                                                 const int* __restrict__ head,
                                                 const int* __restrict__ nxt,
                                                 float* __restrict__ out) {
    int t = threadIdx.x;
    int lane = t & 63;
    int cg = t >> 6;                       // channels cg*16 .. cg*16+15
    int s0 = blockIdx.x * 256 + lane * 4;  // 4 consecutive cells
    int b = s0 / S_CELLS;                  // blocks never straddle batches
    int r0 = s0 - b * S_CELLS;

    const int4 h4 = *(const int4*)&head[s0];
    int hh[4] = {h4.x, h4.y, h4.z, h4.w};

    float acc[4][16];                      // [cell][channel-within-group]
    #pragma unroll
    for (int cell = 0; cell < 4; ++cell)
        #pragma unroll
        for (int i = 0; i < 16; ++i)
            acc[cell][i] = 0.f;

    #pragma unroll
    for (int cell = 0; cell < 4; ++cell) {
        for (int p = hh[cell]; p >= 0; ) {
            int pn = nxt[p];               // hoist: overlap with vf loads
            int pb = p * 16 + cg * 4;      // float4 index into vf
            #pragma unroll
            for (int j = 0; j < 4; ++j) {
                float4 v = vf4[pb + j];
                acc[cell][4 * j + 0] += v.x;
                acc[cell][4 * j + 1] += v.y;
                acc[cell][4 * j + 2] += v.z;
                acc[cell][4 * j + 3] += v.w;
            }
            p = pn;
        }
    }

    size_t outbase = (size_t)b * (CC * S_CELLS)
                   + (size_t)(cg * 16) * S_CELLS + r0;
    #pragma unroll
    for (int i = 0; i < 16; ++i) {
        float4 o = make_float4(acc[0][i], acc[1][i], acc[2][i], acc[3][i]);
        *(float4*)&out[outbase + (size_t)i * S_CELLS] = o;
    }
}

// ---- fallback (round-1 path) if workspace is too small ----
__global__ void pp_zero_kernel(float4* __restrict__ out, int n4) {
    int stride = gridDim.x * blockDim.x;
    for (int i = blockIdx.x * blockDim.x + threadIdx.x; i < n4; i += stride)
        out[i] = make_float4(0.f, 0.f, 0.f, 0.f);
}

__global__ void pp_scatter_kernel(const float* __restrict__ vf,
                                  const int* __restrict__ coords,
                                  float* __restrict__ out,
                                  int total) {
    int tid = blockIdx.x * blockDim.x + threadIdx.x;
    if (tid >= total) return;
    int p = tid >> 6;
    int c = tid & 63;
    int b = coords[p * 4 + 0];
    int y = coords[p * 4 + 2];
    int x = coords[p * 4 + 3];
    float v = vf[tid];
    int idx = (((b * CC + c) * GNY) + y) * GNX + x;
    atomicAdd(&out[idx], v);
}

extern "C" void kernel_launch(void* const* d_in, const int* in_sizes, int n_in,
                              void* d_out, int out_size, void* d_ws, size_t ws_size,
                              hipStream_t stream) {
    const float* vf     = (const float*)d_in[0];
    const int*   coords = (const int*)d_in[1];
    float*       out    = (float*)d_out;

    int total = in_sizes[0];           // P * C
    int P = in_sizes[1] / 4;           // 48000

    size_t need = (size_t)(NUM_CELLS + P) * sizeof(int);
    if (ws_size >= need) {
        int* head = (int*)d_ws;
        int* nxt  = head + NUM_CELLS;

        pp_init_head<<<512, 256, 0, stream>>>((int4*)head, NUM_CELLS / 4);
        pp_build<<<(P + 255) / 256, 256, 0, stream>>>(coords, head, nxt, P);
        pp_gather<<<NUM_CELLS / 256, 256, 0, stream>>>((const float4*)vf, head, nxt, out);
    } else {
        // fallback: zero + atomic scatter
        pp_zero_kernel<<<2048, 256, 0, stream>>>((float4*)out, out_size / 4);
        pp_scatter_kernel<<<(total + 255) / 256, 256, 0, stream>>>(vf, coords, out, total);
    }
}